// Round 10
// baseline (205.373 us; speedup 1.0000x reference)
//
#include <hip/hip_runtime.h>
#include <hip/hip_bf16.h>

// Problem constants: S=2048, B=32, He=Hd=1024, A=512, M = S*B = 65536.

typedef float f32x4 __attribute__((ext_vector_type(4)));
typedef __bf16 bf16x8 __attribute__((ext_vector_type(8)));

// workspace layout (bytes)
#define WS_DEC_OFF    0u                               // 32*512*4       = 65536
#define WS_WIMG_OFF   65536u                           // 32 chunks*32KB = 1048576
#define WS_PART_OFF   (65536u + 1048576u)              // 16*32*1024*4   = 2097152
#define WS_SPART_OFF  WS_PART_OFF                      // 4*32*2048*4 = 1MB, aliases
// (spart written by gemm, read by softmax BEFORE ctx_partial overwrites part)

__device__ __forceinline__ void gload_lds16(const void* g, void* l) {
  __builtin_amdgcn_global_load_lds(
      (const __attribute__((address_space(1))) void*)g,
      (__attribute__((address_space(3))) void*)l, 16, 0, 0);
}

// ---------------------------------------------------------------------------
// dec_att[b][a] = dot(dec_out[b,:], W_dec[a,:])   (32 x 512, K=1024)
__global__ void dec_att_kernel(const float* __restrict__ dec_out,
                               const float* __restrict__ W_dec,
                               float* __restrict__ out) {
  int gtid = blockIdx.x * blockDim.x + threadIdx.x;
  int w = gtid >> 6;
  int lane = gtid & 63;
  int b = w >> 9;          // 0..31
  int a = w & 511;         // 0..511
  const float4* dp = (const float4*)(dec_out + b * 1024);
  const float4* wp = (const float4*)(W_dec + a * 1024);
  float sum = 0.f;
#pragma unroll
  for (int i = 0; i < 4; ++i) {
    float4 x = dp[lane + i * 64];
    float4 y = wp[lane + i * 64];
    sum += x.x * y.x + x.y * y.y + x.z * y.z + x.w * y.w;
  }
#pragma unroll
  for (int m = 32; m; m >>= 1) sum += __shfl_xor(sum, m, 64);
  if (lane == 0) out[b * 512 + a] = sum;
}

// ---------------------------------------------------------------------------
// Pre-convert W_enc into 32 K-chunk images that ARE the GEMM's swizzled LDS
// image: chunk t, row n, 4 slots of 16B; logical slot j stored at j^(n&3).
__global__ void convert_wenc(const float* __restrict__ W, __bf16* __restrict__ out) {
  int idx = blockIdx.x * 256 + threadIdx.x;   // < 524288
  int t = idx >> 14;          // k-chunk 0..31
  int r = (idx >> 5) & 511;   // n row
  int s = (idx >> 3) & 3;     // stored slot
  int e = idx & 7;            // element in slot
  out[idx] = (__bf16)W[r * 1024 + t * 32 + ((s ^ (r & 3)) << 3) + e];
}

// ---------------------------------------------------------------------------
// scores GEMM: BM=128, BN=128 (4 spart slabs), BK=32, 4 waves (2x2), wave
// tile 64x64. LDS all-bf16: A dbuf 2x8KB + B dbuf 2x8KB (+1KB epart) = 33KB
// -> 3 blocks/CU. A: reg-staged (4x dwordx4 f32 -> 8 cvt_pk -> 2 swizzled
// ds_write_b128), cvt ONCE at staging, off the MFMA path. B: global_load_lds
// of the pre-swizzled image. Counted vmcnt(6): stage(t+1)'s 6 vmem ops stay
// in flight across the single per-step barrier; no vmcnt(0) drain in loop.
__global__ __launch_bounds__(256, 3) void scores_gemm(
    const float* __restrict__ enc,        // (65536, 1024) f32
    const __bf16* __restrict__ wimg,      // 32 chunks, swizzled [512][4][16B]
    const float* __restrict__ dec_att,    // [32][512] f32
    const float* __restrict__ attv,       // [512] f32
    float* __restrict__ spart) {          // [4][32][2048] f32 partial scores
  // A dbuf 2x8KB @0, B dbuf 2x8KB @16384, epart @32768 (1KB)
  __shared__ __align__(16) char smem[33792];

  const int tid = threadIdx.x;
  const int lane = tid & 63;
  const int w = tid >> 6;
  const int wr = w >> 1;        // M half
  const int wn = w & 1;         // N half
  const int q = lane >> 4;      // k-slot 0..3
  const int c0 = lane & 15;

  // XCD-aware mapping: the 4 nb-slabs of one bm land on one XCD (L2 A-reuse).
  const int xcd = blockIdx.x & 7;
  const int idx = blockIdx.x >> 3;        // 0..255
  const int bm = xcd + ((idx >> 2) << 3); // 0..511
  const int nb = idx & 3;                 // slab

  f32x4 acc[4][4];
#pragma unroll
  for (int i = 0; i < 4; ++i)
#pragma unroll
    for (int j = 0; j < 4; ++j) acc[i][j] = (f32x4){0.f, 0.f, 0.f, 0.f};

  // ---- A staging: thread owns row = tid>>1 (0..127), k-half kh = tid&1
  // loads 16 f32 (64B) at k = kh*16, writes 2 swizzled bf16 slots (2kh, 2kh+1)
  const int srow = tid >> 1;
  const int kh = tid & 1;
  const float* asrc = enc + ((size_t)(bm * 128 + srow)) * 1024 + kh * 16;
  const int aw0 = srow * 64 + (((2 * kh) ^ (srow & 3)) << 4);
  const int aw1 = srow * 64 + (((2 * kh + 1) ^ (srow & 3)) << 4);
  const char* bsrc0 = (const char*)wimg + nb * 8192 + tid * 16;

  // ---- frag read offsets (swizzled, bf16, rel. to buffer base)
  int a_off[4], b_off[4];
#pragma unroll
  for (int mf = 0; mf < 4; ++mf) {
    const int rl = wr * 64 + mf * 16 + c0;
    a_off[mf] = rl * 64 + ((q ^ (rl & 3)) << 4);
  }
#pragma unroll
  for (int nf = 0; nf < 4; ++nf) {
    const int rn = wn * 64 + nf * 16 + c0;
    b_off[nf] = 16384 + rn * 64 + ((q ^ (rn & 3)) << 4);
  }

  float4 aP0, aP1, aP2, aP3, aQ0, aQ1, aQ2, aQ3;   // named: no scratch

#define LOAD_A(dst0, dst1, dst2, dst3, t)                         \
  { const float4* s4 = (const float4*)(asrc + (t) * 32);          \
    dst0 = s4[0]; dst1 = s4[1]; dst2 = s4[2]; dst3 = s4[3]; }

#define CVT_WRITE_A(buf, s0, s1, s2, s3)                                        \
  { bf16x8 v0, v1;                                                              \
    v0[0] = (__bf16)s0.x; v0[1] = (__bf16)s0.y; v0[2] = (__bf16)s0.z;           \
    v0[3] = (__bf16)s0.w; v0[4] = (__bf16)s1.x; v0[5] = (__bf16)s1.y;           \
    v0[6] = (__bf16)s1.z; v0[7] = (__bf16)s1.w;                                 \
    v1[0] = (__bf16)s2.x; v1[1] = (__bf16)s2.y; v1[2] = (__bf16)s2.z;           \
    v1[3] = (__bf16)s2.w; v1[4] = (__bf16)s3.x; v1[5] = (__bf16)s3.y;           \
    v1[6] = (__bf16)s3.z; v1[7] = (__bf16)s3.w;                                 \
    *(bf16x8*)(smem + (buf) * 8192 + aw0) = v0;                                 \
    *(bf16x8*)(smem + (buf) * 8192 + aw1) = v1; }

  // ---- prologue: A(0)->P, A(1)->Q, B(0)->buf0; wait A(0); cvt+write A(0)
  LOAD_A(aP0, aP1, aP2, aP3, 0);
  LOAD_A(aQ0, aQ1, aQ2, aQ3, 1);
  gload_lds16(bsrc0, smem + 16384 + tid * 16);
  gload_lds16(bsrc0 + 4096, smem + 16384 + 4096 + tid * 16);
  asm volatile("s_waitcnt vmcnt(6)" ::: "memory");   // A(0) landed
  CVT_WRITE_A(0, aP0, aP1, aP2, aP3);
  asm volatile("s_waitcnt lgkmcnt(0)" ::: "memory");
  __builtin_amdgcn_s_barrier();

  // ---- main loop: one barrier per K-step
  for (int t = 0; t < 32; ++t) {
    const int cur = t & 1;
    // issue stage(t+1): A(t+2)->regs (4 loads), B(t+1)->LDS (2 gload_lds)
    {
      const int ta = (t + 2 > 31) ? 31 : t + 2;
      const int tb = (t + 1 > 31) ? 31 : t + 1;
      if (cur == 0) { LOAD_A(aP0, aP1, aP2, aP3, ta); }
      else          { LOAD_A(aQ0, aQ1, aQ2, aQ3, ta); }
      const char* bs = bsrc0 + (size_t)tb * 32768;
      char* bd = smem + 16384 + (cur ^ 1) * 4096 * 2;
      gload_lds16(bs, bd + tid * 16);
      gload_lds16(bs + 4096, bd + 4096 + tid * 16);
    }
    // wait: A(t+1) regs + B(t) LDS landed; stage(t+1)'s 6 stay in flight
    asm volatile("s_waitcnt vmcnt(6)" ::: "memory");
    // cvt + ds_write A(t+1) into buf^1 (published by NEXT step's barrier)
    if (cur == 0) { CVT_WRITE_A(1, aQ0, aQ1, aQ2, aQ3); }
    else          { CVT_WRITE_A(0, aP0, aP1, aP2, aP3); }
    // frags + MFMA(t) from buf[cur]
    bf16x8 af[4], bfr[4];
#pragma unroll
    for (int mf = 0; mf < 4; ++mf)
      af[mf] = *(const bf16x8*)(smem + cur * 8192 + a_off[mf]);
#pragma unroll
    for (int nf = 0; nf < 4; ++nf)
      bfr[nf] = *(const bf16x8*)(smem + cur * 8192 + b_off[nf]);
    __builtin_amdgcn_s_setprio(1);
#pragma unroll
    for (int mf = 0; mf < 4; ++mf)
#pragma unroll
      for (int nf = 0; nf < 4; ++nf)
        acc[mf][nf] = __builtin_amdgcn_mfma_f32_16x16x32_bf16(af[mf], bfr[nf],
                                                              acc[mf][nf], 0, 0, 0);
    __builtin_amdgcn_s_setprio(0);
    // own ds_write + frag reads retired, then publish
    asm volatile("s_waitcnt lgkmcnt(0)" ::: "memory");
    __builtin_amdgcn_s_barrier();
  }

  // ---- epilogue: C/D layout col = lane&15, row = q*4 + reg
  float* epart = (float*)(smem + 32768);   // [128][2]
  float av[4];
#pragma unroll
  for (int nf = 0; nf < 4; ++nf) av[nf] = attv[nb * 128 + wn * 64 + nf * 16 + c0];

#pragma unroll
  for (int mf = 0; mf < 4; ++mf) {
#pragma unroll
    for (int rg = 0; rg < 4; ++rg) {
      const int rl = wr * 64 + mf * 16 + q * 4 + rg;   // local row 0..127
      const int b = rl & 31;
      const float* drow = dec_att + b * 512 + nb * 128 + wn * 64 + c0;
      float sum = 0.f;
#pragma unroll
      for (int nf = 0; nf < 4; ++nf) {
        float x = acc[mf][nf][rg] + drow[nf * 16];
        float e = __expf(2.f * x);                     // tanh(x) = 1 - 2/(e^{2x}+1)
        float th = 1.f - 2.f / (e + 1.f);
        sum += th * av[nf];
      }
      sum += __shfl_xor(sum, 1, 64);
      sum += __shfl_xor(sum, 2, 64);
      sum += __shfl_xor(sum, 4, 64);
      sum += __shfl_xor(sum, 8, 64);
      if (c0 == 0) epart[rl * 2 + wn] = sum;
    }
  }
  __syncthreads();
  if (tid < 128) {
    float tot = epart[tid * 2] + epart[tid * 2 + 1];
    // row r = bm*128 + tid ; s = bm*4 + (tid>>5), b = tid&31
    spart[nb * 65536 + (tid & 31) * 2048 + bm * 4 + (tid >> 5)] = tot;
  }
#undef LOAD_A
#undef CVT_WRITE_A
}

// ---------------------------------------------------------------------------
// softmax over S=2048 per batch row; sums the 4 N-slab partials first.
__global__ void softmax_kernel(const float* __restrict__ spart,
                               float* __restrict__ weights) {
  const int b = blockIdx.x;
  const int t = threadIdx.x;
  const float4* p0 = (const float4*)(spart + b * 2048);
  const float4* p1 = (const float4*)(spart + 65536 + b * 2048);
  const float4* p2 = (const float4*)(spart + 131072 + b * 2048);
  const float4* p3 = (const float4*)(spart + 196608 + b * 2048);
  float4 v0, v1;
  {
    float4 a0 = p0[t], a1 = p1[t], a2 = p2[t], a3 = p3[t];
    v0.x = a0.x + a1.x + a2.x + a3.x; v0.y = a0.y + a1.y + a2.y + a3.y;
    v0.z = a0.z + a1.z + a2.z + a3.z; v0.w = a0.w + a1.w + a2.w + a3.w;
    a0 = p0[t + 256]; a1 = p1[t + 256]; a2 = p2[t + 256]; a3 = p3[t + 256];
    v1.x = a0.x + a1.x + a2.x + a3.x; v1.y = a0.y + a1.y + a2.y + a3.y;
    v1.z = a0.z + a1.z + a2.z + a3.z; v1.w = a0.w + a1.w + a2.w + a3.w;
  }
  float mx = fmaxf(fmaxf(fmaxf(v0.x, v0.y), fmaxf(v0.z, v0.w)),
                   fmaxf(fmaxf(v1.x, v1.y), fmaxf(v1.z, v1.w)));
#pragma unroll
  for (int s = 32; s; s >>= 1) mx = fmaxf(mx, __shfl_xor(mx, s, 64));
  __shared__ float redm[4], reds[4];
  if ((t & 63) == 0) redm[t >> 6] = mx;
  __syncthreads();
  mx = fmaxf(fmaxf(redm[0], redm[1]), fmaxf(redm[2], redm[3]));
  float4 e0, e1;
  e0.x = __expf(v0.x - mx); e0.y = __expf(v0.y - mx);
  e0.z = __expf(v0.z - mx); e0.w = __expf(v0.w - mx);
  e1.x = __expf(v1.x - mx); e1.y = __expf(v1.y - mx);
  e1.z = __expf(v1.z - mx); e1.w = __expf(v1.w - mx);
  float s8 = e0.x + e0.y + e0.z + e0.w + e1.x + e1.y + e1.z + e1.w;
#pragma unroll
  for (int s = 32; s; s >>= 1) s8 += __shfl_xor(s8, s, 64);
  if ((t & 63) == 0) reds[t >> 6] = s8;
  __syncthreads();
  float inv = 1.f / (reds[0] + reds[1] + reds[2] + reds[3]);
  e0.x *= inv; e0.y *= inv; e0.z *= inv; e0.w *= inv;
  e1.x *= inv; e1.y *= inv; e1.z *= inv; e1.w *= inv;
  float4* wrow = (float4*)(weights + b * 2048);
  wrow[t] = e0;
  wrow[t + 256] = e1;
}

// ---------------------------------------------------------------------------
// context partials: block = (b, s-chunk of 128); thread owns float4 at h=t*4
__global__ void ctx_partial(const float* __restrict__ enc,
                            const float* __restrict__ weights,
                            float* __restrict__ part) {
  const int b = blockIdx.x & 31;
  const int sc = blockIdx.x >> 5;       // 0..15
  const int t = threadIdx.x;
  const float* wrow = weights + b * 2048 + sc * 128;
  const char* ebase = (const char*)(enc + ((size_t)(sc * 128) * 32 + b) * 1024) + t * 16;
  float4 acc = {0.f, 0.f, 0.f, 0.f};
#pragma unroll 4
  for (int i = 0; i < 128; ++i) {
    float4 e = *(const float4*)(ebase + (size_t)i * 131072);
    float ws = wrow[i];
    acc.x += ws * e.x; acc.y += ws * e.y; acc.z += ws * e.z; acc.w += ws * e.w;
  }
  *(float4*)(part + (size_t)(sc * 32 + b) * 1024 + t * 4) = acc;
}

__global__ void ctx_reduce(const float* __restrict__ part, float* __restrict__ ctx) {
  int idx = blockIdx.x * 256 + threadIdx.x;   // < 32768
  float s = 0.f;
#pragma unroll
  for (int c = 0; c < 16; ++c) s += part[c * 32768 + idx];
  ctx[idx] = s;
}

// ---------------------------------------------------------------------------
extern "C" void kernel_launch(void* const* d_in, const int* in_sizes, int n_in,
                              void* d_out, int out_size, void* d_ws, size_t ws_size,
                              hipStream_t stream) {
  const float* dec_out  = (const float*)d_in[0];   // (32, 1024)
  const float* enc_outs = (const float*)d_in[1];   // (2048, 32, 1024)
  const float* W_enc    = (const float*)d_in[2];   // (512, 1024)
  const float* W_dec    = (const float*)d_in[3];   // (512, 1024)
  const float* att_v    = (const float*)d_in[4];   // (512,)

  float* out = (float*)d_out;
  float* ctx = out;                 // (32,1024) = 32768 floats
  float* weights = out + 32768;     // (32,2048) = 65536 floats

  char* ws = (char*)d_ws;
  float*  ws_dec    = (float*)(ws + WS_DEC_OFF);
  __bf16* ws_wimg   = (__bf16*)(ws + WS_WIMG_OFF);
  float*  ws_spart  = (float*)(ws + WS_SPART_OFF);  // aliases ws_part (read before part written)
  float*  ws_part   = (float*)(ws + WS_PART_OFF);

  dec_att_kernel<<<4096, 256, 0, stream>>>(dec_out, W_dec, ws_dec);
  convert_wenc<<<2048, 256, 0, stream>>>(W_enc, ws_wimg);
  scores_gemm<<<2048, 256, 0, stream>>>(enc_outs, ws_wimg, ws_dec, att_v, ws_spart);
  softmax_kernel<<<32, 256, 0, stream>>>(ws_spart, weights);
  ctx_partial<<<512, 256, 0, stream>>>(enc_outs, weights, ws_part);
  ctx_reduce<<<128, 256, 0, stream>>>(ws_part, ctx);
}

// Round 11
// 174.707 us; speedup vs baseline: 1.1755x; 1.1755x over previous
//
#include <hip/hip_runtime.h>
#include <hip/hip_bf16.h>

// Problem constants: S=2048, B=32, He=Hd=1024, A=512, M = S*B = 65536.

typedef float f32x4 __attribute__((ext_vector_type(4)));
typedef __bf16 bf16x8 __attribute__((ext_vector_type(8)));

// workspace layout (bytes)
#define WS_DEC_OFF    0u                               // 32*512*4       = 65536
#define WS_WIMG_OFF   65536u                           // 32 chunks*32KB = 1048576
#define WS_PART_OFF   (65536u + 1048576u)              // 16*32*1024*4   = 2097152
#define WS_SPART_OFF  WS_PART_OFF                      // 2*32*2048*4 = 512KB, aliases
// (spart written by gemm, read by softmax BEFORE ctx_partial overwrites part)

__device__ __forceinline__ void gload_lds16(const void* g, void* l) {
  __builtin_amdgcn_global_load_lds(
      (const __attribute__((address_space(1))) void*)g,
      (__attribute__((address_space(3))) void*)l, 16, 0, 0);
}

// ---------------------------------------------------------------------------
// dec_att[b][a] = dot(dec_out[b,:], W_dec[a,:])   (32 x 512, K=1024)
__global__ void dec_att_kernel(const float* __restrict__ dec_out,
                               const float* __restrict__ W_dec,
                               float* __restrict__ out) {
  int gtid = blockIdx.x * blockDim.x + threadIdx.x;
  int w = gtid >> 6;
  int lane = gtid & 63;
  int b = w >> 9;          // 0..31
  int a = w & 511;         // 0..511
  const float4* dp = (const float4*)(dec_out + b * 1024);
  const float4* wp = (const float4*)(W_dec + a * 1024);
  float sum = 0.f;
#pragma unroll
  for (int i = 0; i < 4; ++i) {
    float4 x = dp[lane + i * 64];
    float4 y = wp[lane + i * 64];
    sum += x.x * y.x + x.y * y.y + x.z * y.z + x.w * y.w;
  }
#pragma unroll
  for (int m = 32; m; m >>= 1) sum += __shfl_xor(sum, m, 64);
  if (lane == 0) out[b * 512 + a] = sum;
}

// ---------------------------------------------------------------------------
// Pre-convert W_enc (512x1024 f32) into 32 K-chunk images of layout
// [q=ksub 0..3][row 0..511][8 bf16]  (32 KB per chunk): the GEMM's LDS image.
// elem (kc,q,row,j) = W[row][kc*32 + q*8 + j]
__global__ void convert_wenc(const float* __restrict__ W, __bf16* __restrict__ out) {
  int idx = blockIdx.x * 256 + threadIdx.x;   // < 524288
  int kc = idx >> 14;
  int q = (idx >> 12) & 3;
  int row = (idx >> 3) & 511;
  int j = idx & 7;
  out[idx] = (__bf16)W[row * 1024 + kc * 32 + q * 8 + j];
}

// ---------------------------------------------------------------------------
// scores GEMM (R3 schedule + higher occupancy): BM=64, BN=256 (2 spart
// slabs), BK=32, 4 waves each owning a 64x64 sub-tile (acc 4x4 f32x4).
// LDS 41KB: A dbuf 2x4KB (bf16, XOR-swizzled slots), B dbuf 2x16KB
// ([q][256][16B] plane layout, staged linearly via global_load_lds,
// conflict-free reads). Schedule per K-step: issue stage(t+1) ->
// frags(t) -> MFMA(t) -> cvt+ds_write A(t+1) -> __syncthreads.
// launch_bounds(256,3) => 3 blocks/CU (12 waves/CU).
__global__ __launch_bounds__(256, 3) void scores_gemm(
    const float* __restrict__ enc,        // (65536, 1024) f32
    const __bf16* __restrict__ wimg,      // 32 chunks of [4][512][16B] bf16
    const float* __restrict__ dec_att,    // [32][512] f32
    const float* __restrict__ attv,       // [512] f32
    float* __restrict__ spart) {          // [2][32][2048] f32 partial scores
  // A dbuf 2x4096 @0, B dbuf 2x16384 @8192, epart [64][4] f32 @40960
  __shared__ __align__(16) char smem[41984];

  const int tid = threadIdx.x;
  const int lane = tid & 63;
  const int w = tid >> 6;       // wave 0..3 = 64-col quarter of the slab
  const int q = lane >> 4;      // k-slot 0..3
  const int c0 = lane & 15;

  // XCD-aware mapping: both nb-slabs of one bm (and 128 consecutive bm
  // pairs) land on one XCD -> A rows L2-shared across the 2 slabs.
  const int xcd = blockIdx.x & 7;
  const int idx = blockIdx.x >> 3;        // 0..255
  const int bm = xcd + ((idx >> 1) << 3); // 0..1023
  const int nb = idx & 1;                 // slab

  f32x4 acc[4][4];
#pragma unroll
  for (int i = 0; i < 4; ++i)
#pragma unroll
    for (int j = 0; j < 4; ++j) acc[i][j] = (f32x4){0.f, 0.f, 0.f, 0.f};

  // ---- A staging: thread owns row srow = tid>>2 (0..63), k-sub sq = tid&3
  const int srow = tid >> 2;
  const int sq = tid & 3;
  const float* asrc = enc + (size_t)(bm * 64 + srow) * 1024 + sq * 8;
  const int a_woff = srow * 64 + (((sq ^ (srow & 3)) << 4));

  // ---- B staging: thread copies plane tid>>6, rows (tid&63)+p*64 of the
  // block's slab (global rows nb*256 + r). Wave-uniform base + lane*16. ✓
  const char* bsrc = (const char*)wimg + (tid >> 6) * 8192 + nb * 4096 + (tid & 63) * 16;
  const int b_dst = (tid >> 6) * 4096 + (tid & 63) * 16;

  // ---- frag read offsets
  int a_off[4], b_off[4];
#pragma unroll
  for (int mf = 0; mf < 4; ++mf) {
    const int rl = mf * 16 + c0;
    a_off[mf] = rl * 64 + ((q ^ (rl & 3)) << 4);
  }
#pragma unroll
  for (int nf = 0; nf < 4; ++nf) {
    const int rn = w * 64 + nf * 16 + c0;   // row within slab
    b_off[nf] = q * 4096 + rn * 16;
  }

  // ---- prologue: A(0)->regs->cvt->LDS buf0, B(0)->buf0
  {
    const float4* s4 = (const float4*)asrc;
    float4 x = s4[0], y = s4[1];
#pragma unroll
    for (int p = 0; p < 4; ++p)
      gload_lds16(bsrc + p * 1024, smem + 8192 + b_dst + p * 1024);
    bf16x8 v;
    v[0] = (__bf16)x.x; v[1] = (__bf16)x.y; v[2] = (__bf16)x.z; v[3] = (__bf16)x.w;
    v[4] = (__bf16)y.x; v[5] = (__bf16)y.y; v[6] = (__bf16)y.z; v[7] = (__bf16)y.w;
    *(bf16x8*)(smem + a_woff) = v;
  }
  __syncthreads();

  // ---- main loop (R3 schedule, one __syncthreads per K-step)
  for (int t = 0; t < 32; ++t) {
    const int cur = t & 1;
    float4 nx, ny;
    if (t < 31) {
      const float4* s4 = (const float4*)(asrc + (t + 1) * 32);
      nx = s4[0]; ny = s4[1];
      const char* bs = bsrc + (size_t)(t + 1) * 32768;
      char* bd = smem + 8192 + (cur ^ 1) * 16384 + b_dst;
#pragma unroll
      for (int p = 0; p < 4; ++p)
        gload_lds16(bs + p * 1024, bd + p * 1024);
    }
    // fragments for tile t
    bf16x8 af[4], bfr[4];
#pragma unroll
    for (int mf = 0; mf < 4; ++mf)
      af[mf] = *(const bf16x8*)(smem + cur * 4096 + a_off[mf]);
#pragma unroll
    for (int nf = 0; nf < 4; ++nf)
      bfr[nf] = *(const bf16x8*)(smem + 8192 + cur * 16384 + b_off[nf]);
    __builtin_amdgcn_s_setprio(1);
#pragma unroll
    for (int mf = 0; mf < 4; ++mf)
#pragma unroll
      for (int nf = 0; nf < 4; ++nf)
        acc[mf][nf] = __builtin_amdgcn_mfma_f32_16x16x32_bf16(af[mf], bfr[nf],
                                                              acc[mf][nf], 0, 0, 0);
    __builtin_amdgcn_s_setprio(0);
    // finish A stage for t+1 (cvt + swizzled ds_write into alt buffer)
    if (t < 31) {
      bf16x8 v;
      v[0] = (__bf16)nx.x; v[1] = (__bf16)nx.y; v[2] = (__bf16)nx.z; v[3] = (__bf16)nx.w;
      v[4] = (__bf16)ny.x; v[5] = (__bf16)ny.y; v[6] = (__bf16)ny.z; v[7] = (__bf16)ny.w;
      *(bf16x8*)(smem + (cur ^ 1) * 4096 + a_woff) = v;
    }
    __syncthreads();
  }

  // ---- epilogue: C/D layout col = lane&15, row = q*4 + reg
  float* epart = (float*)(smem + 40960);   // [64][4]
  float av[4];
#pragma unroll
  for (int nf = 0; nf < 4; ++nf) av[nf] = attv[nb * 256 + w * 64 + nf * 16 + c0];

#pragma unroll
  for (int mf = 0; mf < 4; ++mf) {
#pragma unroll
    for (int rg = 0; rg < 4; ++rg) {
      const int rl = mf * 16 + q * 4 + rg;             // local row 0..63
      const int b = rl & 31;                           // row = s*32+b (bm*64%32==0)
      const float* drow = dec_att + b * 512 + nb * 256 + w * 64 + c0;
      float sum = 0.f;
#pragma unroll
      for (int nf = 0; nf < 4; ++nf) {
        float x = acc[mf][nf][rg] + drow[nf * 16];
        float e = __expf(2.f * x);                     // tanh(x) = 1 - 2/(e^{2x}+1)
        float th = 1.f - 2.f / (e + 1.f);
        sum += th * av[nf];
      }
      sum += __shfl_xor(sum, 1, 64);
      sum += __shfl_xor(sum, 2, 64);
      sum += __shfl_xor(sum, 4, 64);
      sum += __shfl_xor(sum, 8, 64);
      if (c0 == 0) epart[rl * 4 + w] = sum;
    }
  }
  __syncthreads();
  if (tid < 64) {
    float tot = epart[tid * 4] + epart[tid * 4 + 1] +
                epart[tid * 4 + 2] + epart[tid * 4 + 3];
    // global row r = bm*64 + tid; s = bm*2 + (tid>>5), b = tid&31
    spart[nb * 65536 + (tid & 31) * 2048 + bm * 2 + (tid >> 5)] = tot;
  }
}

// ---------------------------------------------------------------------------
// softmax over S=2048 per batch row; sums the 2 N-slab partials first.
__global__ void softmax_kernel(const float* __restrict__ spart,
                               float* __restrict__ weights) {
  const int b = blockIdx.x;
  const int t = threadIdx.x;
  const float4* p0 = (const float4*)(spart + b * 2048);
  const float4* p1 = (const float4*)(spart + 65536 + b * 2048);
  float4 v0, v1;
  {
    float4 a0 = p0[t], a1 = p1[t];
    v0.x = a0.x + a1.x; v0.y = a0.y + a1.y; v0.z = a0.z + a1.z; v0.w = a0.w + a1.w;
    a0 = p0[t + 256]; a1 = p1[t + 256];
    v1.x = a0.x + a1.x; v1.y = a0.y + a1.y; v1.z = a0.z + a1.z; v1.w = a0.w + a1.w;
  }
  float mx = fmaxf(fmaxf(fmaxf(v0.x, v0.y), fmaxf(v0.z, v0.w)),
                   fmaxf(fmaxf(v1.x, v1.y), fmaxf(v1.z, v1.w)));
#pragma unroll
  for (int s = 32; s; s >>= 1) mx = fmaxf(mx, __shfl_xor(mx, s, 64));
  __shared__ float redm[4], reds[4];
  if ((t & 63) == 0) redm[t >> 6] = mx;
  __syncthreads();
  mx = fmaxf(fmaxf(redm[0], redm[1]), fmaxf(redm[2], redm[3]));
  float4 e0, e1;
  e0.x = __expf(v0.x - mx); e0.y = __expf(v0.y - mx);
  e0.z = __expf(v0.z - mx); e0.w = __expf(v0.w - mx);
  e1.x = __expf(v1.x - mx); e1.y = __expf(v1.y - mx);
  e1.z = __expf(v1.z - mx); e1.w = __expf(v1.w - mx);
  float s8 = e0.x + e0.y + e0.z + e0.w + e1.x + e1.y + e1.z + e1.w;
#pragma unroll
  for (int s = 32; s; s >>= 1) s8 += __shfl_xor(s8, s, 64);
  if ((t & 63) == 0) reds[t >> 6] = s8;
  __syncthreads();
  float inv = 1.f / (reds[0] + reds[1] + reds[2] + reds[3]);
  e0.x *= inv; e0.y *= inv; e0.z *= inv; e0.w *= inv;
  e1.x *= inv; e1.y *= inv; e1.z *= inv; e1.w *= inv;
  float4* wrow = (float4*)(weights + b * 2048);
  wrow[t] = e0;
  wrow[t + 256] = e1;
}

// ---------------------------------------------------------------------------
// context partials: block = (b, s-chunk of 128); thread owns float4 at h=t*4
__global__ void ctx_partial(const float* __restrict__ enc,
                            const float* __restrict__ weights,
                            float* __restrict__ part) {
  const int b = blockIdx.x & 31;
  const int sc = blockIdx.x >> 5;       // 0..15
  const int t = threadIdx.x;
  const float* wrow = weights + b * 2048 + sc * 128;
  const char* ebase = (const char*)(enc + ((size_t)(sc * 128) * 32 + b) * 1024) + t * 16;
  float4 acc = {0.f, 0.f, 0.f, 0.f};
#pragma unroll 4
  for (int i = 0; i < 128; ++i) {
    float4 e = *(const float4*)(ebase + (size_t)i * 131072);
    float ws = wrow[i];
    acc.x += ws * e.x; acc.y += ws * e.y; acc.z += ws * e.z; acc.w += ws * e.w;
  }
  *(float4*)(part + (size_t)(sc * 32 + b) * 1024 + t * 4) = acc;
}

__global__ void ctx_reduce(const float* __restrict__ part, float* __restrict__ ctx) {
  int idx = blockIdx.x * 256 + threadIdx.x;   // < 32768
  float s = 0.f;
#pragma unroll
  for (int c = 0; c < 16; ++c) s += part[c * 32768 + idx];
  ctx[idx] = s;
}

// ---------------------------------------------------------------------------
extern "C" void kernel_launch(void* const* d_in, const int* in_sizes, int n_in,
                              void* d_out, int out_size, void* d_ws, size_t ws_size,
                              hipStream_t stream) {
  const float* dec_out  = (const float*)d_in[0];   // (32, 1024)
  const float* enc_outs = (const float*)d_in[1];   // (2048, 32, 1024)
  const float* W_enc    = (const float*)d_in[2];   // (512, 1024)
  const float* W_dec    = (const float*)d_in[3];   // (512, 1024)
  const float* att_v    = (const float*)d_in[4];   // (512,)

  float* out = (float*)d_out;
  float* ctx = out;                 // (32,1024) = 32768 floats
  float* weights = out + 32768;     // (32,2048) = 65536 floats

  char* ws = (char*)d_ws;
  float*  ws_dec    = (float*)(ws + WS_DEC_OFF);
  __bf16* ws_wimg   = (__bf16*)(ws + WS_WIMG_OFF);
  float*  ws_spart  = (float*)(ws + WS_SPART_OFF);  // aliases ws_part (read before part written)
  float*  ws_part   = (float*)(ws + WS_PART_OFF);

  dec_att_kernel<<<4096, 256, 0, stream>>>(dec_out, W_dec, ws_dec);
  convert_wenc<<<2048, 256, 0, stream>>>(W_enc, ws_wimg);
  scores_gemm<<<2048, 256, 0, stream>>>(enc_outs, ws_wimg, ws_dec, att_v, ws_spart);
  softmax_kernel<<<32, 256, 0, stream>>>(ws_spart, weights);
  ctx_partial<<<512, 256, 0, stream>>>(enc_outs, weights, ws_part);
  ctx_reduce<<<128, 256, 0, stream>>>(ws_part, ctx);
}